// Round 8
// baseline (106.370 us; speedup 1.0000x reference)
//
#include <hip/hip_runtime.h>

// MultiModalFusion collapses analytically:
//   q[b,n,m,s,k] = x[b,n,m,s]*A_k + bq_k   (A_k = sum_d Wq[k,d]; same C_k/Wk, E_k/Wv)
//   scores(s,t)  = (x_s*x_t*(A.C) + x_s*(A.bk) + x_t*(C.bq) + bq.bk)/8
//   softmax over t drops terms constant in t -> attn = softmax_t(c_s * x_j[t]),
//       c_s = alpha*x_i[s] + gamma,  alpha=(A.C)/8, gamma=(C.bq)/8
//   mean over k of PV: Ebar * sum_t attn*x_j[t] + bvbar
//   out[b,n,i,s] = Ebar * mean_{j!=i} y_j(c_s) + bvbar
//
// Fused single kernel: wave 0 recomputes the 4 scalars per block (W reads are
// L2-hot, ~96 KB) while all threads stage x into LDS; saves the dependent
// mm_prep dispatch (~3-5 us of graph launch serialization) and d_ws entirely.

#if __has_builtin(__builtin_amdgcn_exp2f)
#define EXP2(v) __builtin_amdgcn_exp2f(v)
#else
#define EXP2(v) exp2f(v)
#endif

static __device__ __forceinline__ float hsum4(float4 v) { return (v.x + v.y) + (v.z + v.w); }

// One block per (b,n,i): 256 threads, thread = s.
__global__ __launch_bounds__(256) void mm_fused(const float* __restrict__ x,
                                                const float* __restrict__ Wq,
                                                const float* __restrict__ bq,
                                                const float* __restrict__ Wk,
                                                const float* __restrict__ bk,
                                                const float* __restrict__ Wv,
                                                const float* __restrict__ bv,
                                                float* __restrict__ out) {
    __shared__ float xs[4][256];
    __shared__ float scal[4];
    const int bni = blockIdx.x;          // ((b*51+n)*4 + i)
    const int i   = bni & 3;
    const int tid = threadIdx.x;
    const float* xb = x + (size_t)(bni >> 2) * 1024;
    #pragma unroll
    for (int r = 0; r < 4; ++r) xs[r][tid] = xb[r * 256 + tid];

    if (tid < 64) {                      // wave 0: per-block scalar prep
        const int k = tid;
        const float4* wq4 = reinterpret_cast<const float4*>(Wq) + k * 32;
        const float4* wk4 = reinterpret_cast<const float4*>(Wk) + k * 32;
        const float4* wv4 = reinterpret_cast<const float4*>(Wv) + k * 32;
        float a = 0.f, c = 0.f, e = 0.f;
        #pragma unroll 8
        for (int d = 0; d < 32; ++d) {
            a += hsum4(wq4[d]);
            c += hsum4(wk4[d]);
            e += hsum4(wv4[d]);
        }
        float dac = a * c;               // -> alpha after reduce
        float dcq = c * bq[k];           // -> gamma after reduce
        float sbv = bv[k];
        #pragma unroll
        for (int off = 32; off > 0; off >>= 1) {
            dac += __shfl_down(dac, off, 64);
            dcq += __shfl_down(dcq, off, 64);
            e   += __shfl_down(e,   off, 64);
            sbv += __shfl_down(sbv, off, 64);
        }
        if (k == 0) {
            scal[0] = dac * 0.125f;          // alpha
            scal[1] = dcq * 0.125f;          // gamma
            scal[2] = e   * (1.0f / 64.0f);  // Ebar
            scal[3] = sbv * (1.0f / 64.0f);  // bvbar
        }
    }
    __syncthreads();

    const float alpha = scal[0], gamma = scal[1], Ebar = scal[2], bvbar = scal[3];
    // fold log2(e) so the HW exp2 pipe does the work
    const float c2 = (alpha * xs[i][tid] + gamma) * 1.4426950408889634f;

    float acc = 0.f;
    #pragma unroll
    for (int jj = 1; jj < 4; ++jj) {
        const int j = (i + jj) & 3;                 // uniform across the block
        const float4* xj = reinterpret_cast<const float4*>(xs[j]);
        // 4 independent num accumulators + 2 den accumulators: no serial
        // fmaf chain, keeps 8+ exps in flight for the 8-cyc trans pipe.
        float n0 = 0.f, n1 = 0.f, n2 = 0.f, n3 = 0.f, d0 = 0.f, d1 = 0.f;
        #pragma unroll 4
        for (int t = 0; t < 64; ++t) {              // 256 elements as float4
            float4 v = xj[t];                       // LDS wave-uniform broadcast
            float w0 = EXP2(c2 * v.x);
            float w1 = EXP2(c2 * v.y);
            float w2 = EXP2(c2 * v.z);
            float w3 = EXP2(c2 * v.w);
            n0 = fmaf(w0, v.x, n0);
            n1 = fmaf(w1, v.y, n1);
            n2 = fmaf(w2, v.z, n2);
            n3 = fmaf(w3, v.w, n3);
            d0 += w0 + w2;
            d1 += w1 + w3;
        }
        acc += ((n0 + n1) + (n2 + n3)) / (d0 + d1);
    }
    out[(size_t)bni * 256 + tid] = fmaf(Ebar * (1.0f / 3.0f), acc, bvbar);
}

extern "C" void kernel_launch(void* const* d_in, const int* in_sizes, int n_in,
                              void* d_out, int out_size, void* d_ws, size_t ws_size,
                              hipStream_t stream) {
    const float* x  = (const float*)d_in[0];
    const float* Wq = (const float*)d_in[1];
    const float* bq = (const float*)d_in[2];
    const float* Wk = (const float*)d_in[3];
    const float* bk = (const float*)d_in[4];
    const float* Wv = (const float*)d_in[5];
    const float* bv = (const float*)d_in[6];
    float* out = (float*)d_out;

    mm_fused<<<816, 256, 0, stream>>>(x, Wq, bq, Wk, bk, Wv, bv, out);
}

// Round 10
// 105.014 us; speedup vs baseline: 1.0129x; 1.0129x over previous
//
#include <hip/hip_runtime.h>

// MultiModalFusion collapses analytically:
//   q[b,n,m,s,k] = x[b,n,m,s]*A_k + bq_k   (A_k = sum_d Wq[k,d]; same C_k/Wk, E_k/Wv)
//   softmax over t drops terms constant in t -> attn = softmax_t(c_s * x_j[t]),
//       c_s = alpha*x_i[s] + gamma,  alpha=(A.C)/8, gamma=(C.bq)/8
//   out[b,n,i,s] = Ebar * mean_{j!=i} [ (sum_t e^{c x_jt} x_jt) / (sum_t e^{c x_jt}) ] + bvbar
//
// Round-8 postmortem: kernel was LATENCY-bound (VALUBusy 41%, Occ 22%,
// 3.2 waves/SIMD). This version: (a) prep back in its own 1-wave kernel
// (fused per-block prep was a measured regression 99->106 us),
// (b) 512 threads/block with a 2-way t-split + LDS combine -> 25.5 waves/CU
// all-resident, 2x latency hiding at identical total work.

#if __has_builtin(__builtin_amdgcn_exp2f)
#define EXP2(v) __builtin_amdgcn_exp2f(v)
#else
#define EXP2(v) exp2f(v)
#endif

static __device__ __forceinline__ float hsum4(float4 v) { return (v.x + v.y) + (v.z + v.w); }

// One wave: compute the 4 scalars into sc[0..3].
__global__ void mm_prep(const float* __restrict__ Wq, const float* __restrict__ bq,
                        const float* __restrict__ Wk, const float* __restrict__ bk,
                        const float* __restrict__ Wv, const float* __restrict__ bv,
                        float* __restrict__ sc) {
    const int k = threadIdx.x;  // 0..63
    const float4* wq4 = reinterpret_cast<const float4*>(Wq) + k * 32;
    const float4* wk4 = reinterpret_cast<const float4*>(Wk) + k * 32;
    const float4* wv4 = reinterpret_cast<const float4*>(Wv) + k * 32;
    float a = 0.f, c = 0.f, e = 0.f;
    #pragma unroll 8
    for (int d = 0; d < 32; ++d) {
        a += hsum4(wq4[d]);
        c += hsum4(wk4[d]);
        e += hsum4(wv4[d]);
    }
    float dac = a * c;         // -> alpha after reduce
    float dcq = c * bq[k];     // -> gamma after reduce
    float sbv = bv[k];
    #pragma unroll
    for (int off = 32; off > 0; off >>= 1) {
        dac += __shfl_down(dac, off, 64);
        dcq += __shfl_down(dcq, off, 64);
        e   += __shfl_down(e,   off, 64);
        sbv += __shfl_down(sbv, off, 64);
    }
    if (k == 0) {
        sc[0] = dac * 0.125f;          // alpha
        sc[1] = dcq * 0.125f;          // gamma
        sc[2] = e   * (1.0f / 64.0f);  // Ebar
        sc[3] = sbv * (1.0f / 64.0f);  // bvbar
    }
}

// One block per (b,n,i): 512 threads = (h, s), h = t-range half, s = query pos.
__global__ __launch_bounds__(512) void mm_attn(const float* __restrict__ x,
                                               const float* __restrict__ sc,
                                               float* __restrict__ out) {
    __shared__ float xs[4][256];
    __shared__ float pn[2][3][256];   // partial numerators  [half][jj][s]
    __shared__ float pd[2][3][256];   // partial denominators
    const int bni = blockIdx.x;       // ((b*51+n)*4 + i)
    const int i   = bni & 3;
    const int tid = threadIdx.x;      // 0..511
    const int s   = tid & 255;
    const int h   = tid >> 8;         // 0 or 1
    const float* xb = x + (size_t)(bni >> 2) * 1024;
    #pragma unroll
    for (int r = 0; r < 2; ++r) xs[2 * h + r][s] = xb[(2 * h + r) * 256 + s];
    __syncthreads();

    const float alpha = sc[0], gamma = sc[1], Ebar = sc[2], bvbar = sc[3];
    // fold log2(e) so the HW exp2 pipe does the work
    const float c2 = (alpha * xs[i][s] + gamma) * 1.4426950408889634f;

    #pragma unroll
    for (int jj = 1; jj < 4; ++jj) {
        const int j = (i + jj) & 3;                       // uniform across block
        const float4* xj = reinterpret_cast<const float4*>(xs[j]) + h * 32;
        // 4 independent num chains + 2 den chains: keeps >=8 exps in flight.
        float n0 = 0.f, n1 = 0.f, n2 = 0.f, n3 = 0.f, d0 = 0.f, d1 = 0.f;
        #pragma unroll 8
        for (int t = 0; t < 32; ++t) {                    // 128 elems as float4
            float4 v = xj[t];                             // wave-uniform LDS broadcast
            float w0 = EXP2(c2 * v.x);
            float w1 = EXP2(c2 * v.y);
            float w2 = EXP2(c2 * v.z);
            float w3 = EXP2(c2 * v.w);
            n0 = fmaf(w0, v.x, n0);
            n1 = fmaf(w1, v.y, n1);
            n2 = fmaf(w2, v.z, n2);
            n3 = fmaf(w3, v.w, n3);
            d0 += w0 + w2;
            d1 += w1 + w3;
        }
        pn[h][jj - 1][s] = (n0 + n1) + (n2 + n3);
        pd[h][jj - 1][s] = d0 + d1;
    }
    __syncthreads();

    if (tid < 256) {
        float acc = 0.f;
        #pragma unroll
        for (int jj = 0; jj < 3; ++jj)
            acc += (pn[0][jj][tid] + pn[1][jj][tid]) / (pd[0][jj][tid] + pd[1][jj][tid]);
        out[(size_t)bni * 256 + tid] = fmaf(Ebar * (1.0f / 3.0f), acc, bvbar);
    }
}

extern "C" void kernel_launch(void* const* d_in, const int* in_sizes, int n_in,
                              void* d_out, int out_size, void* d_ws, size_t ws_size,
                              hipStream_t stream) {
    const float* x  = (const float*)d_in[0];
    const float* Wq = (const float*)d_in[1];
    const float* bq = (const float*)d_in[2];
    const float* Wk = (const float*)d_in[3];
    const float* bk = (const float*)d_in[4];
    const float* Wv = (const float*)d_in[5];
    const float* bv = (const float*)d_in[6];
    float* out = (float*)d_out;
    float* sc  = (float*)d_ws;   // 4 floats of scratch

    mm_prep<<<1, 64, 0, stream>>>(Wq, bq, Wk, bk, Wv, bv, sc);
    mm_attn<<<816, 512, 0, stream>>>(x, sc, out);
}